// Round 1
// baseline (61.371 us; speedup 1.0000x reference)
//
#include <hip/hip_runtime.h>

// RankLoss: loss = -mean_b( 1 / (sum_j sigmoid(x[b,j] - x[b,0]) + 0.5) )
// Only row i=0 of the pairwise matrix is consumed by the reference, so the
// minimal computation is O(B*N), not O(B*N^2).
//
// B=32, N=2048. Single block, 1024 threads = 16 waves.
// Wave w handles batches w and w+16 (one row each pass):
//   lane-strided coalesced loads, per-lane partial sigmoid sum,
//   64-lane shuffle reduction, rr_b -> LDS, thread 0 writes -mean.

#define RL_B 32
#define RL_N 2048

__global__ __launch_bounds__(1024) void RankLoss_73959336837390_kernel(
    const float* __restrict__ x, float* __restrict__ out) {
    __shared__ float rr_s[RL_B];

    const int tid  = threadIdx.x;
    const int wave = tid >> 6;   // 0..15
    const int lane = tid & 63;   // 0..63

    #pragma unroll
    for (int rep = 0; rep < 2; ++rep) {
        const int b = wave + rep * 16;
        const float* __restrict__ row = x + b * RL_N;
        const float x0 = row[0];

        float sum = 0.0f;
        #pragma unroll 4
        for (int j = lane; j < RL_N; j += 64) {
            const float d = row[j] - x0;
            // sigmoid(d) = 1 / (1 + exp(-d))
            sum += 1.0f / (1.0f + __expf(-d));
        }

        // 64-lane wave reduction
        #pragma unroll
        for (int off = 32; off > 0; off >>= 1)
            sum += __shfl_down(sum, off, 64);

        if (lane == 0)
            rr_s[b] = 1.0f / (sum + 0.5f);
    }

    __syncthreads();

    if (tid == 0) {
        float acc = 0.0f;
        #pragma unroll
        for (int b = 0; b < RL_B; ++b) acc += rr_s[b];
        *out = -acc / (float)RL_B;
    }
}

extern "C" void kernel_launch(void* const* d_in, const int* in_sizes, int n_in,
                              void* d_out, int out_size, void* d_ws, size_t ws_size,
                              hipStream_t stream) {
    const float* x = (const float*)d_in[0];
    float* out = (float*)d_out;
    RankLoss_73959336837390_kernel<<<1, 1024, 0, stream>>>(x, out);
}

// Round 2
// 60.986 us; speedup vs baseline: 1.0063x; 1.0063x over previous
//
#include <hip/hip_runtime.h>

// RankLoss: loss = -mean_b( 1 / (sum_j sigmoid(x[b,j] - x[b,0]) + 0.5) )
// Only row i=0 of the pairwise matrix is consumed, so the minimal
// computation is O(B*N) = 32*2048 sigmoids.
//
// Single kernel node (graph-replay overhead is dominated by the harness's
// 268 MB d_ws re-poison fill, ~40 us; keep our contribution minimal).
// 1 block x 1024 threads = 16 waves. Wave w handles rows w and w+16.
// All 16 float4 loads per lane are issued BEFORE any compute: 16 x 16 B
// in flight per lane hides the L2/L3 latency that bound the previous
// scalar unroll-4 version.

#define RL_B 32
#define RL_N 2048

__device__ __forceinline__ float sig(float d) {
    return 1.0f / (1.0f + __expf(-d));
}

__global__ __launch_bounds__(1024) void RankLoss_73959336837390_kernel(
    const float* __restrict__ x, float* __restrict__ out) {
    __shared__ float rr_s[RL_B];

    const int tid  = threadIdx.x;
    const int wave = tid >> 6;   // 0..15
    const int lane = tid & 63;   // 0..63

    const int b0 = wave;
    const int b1 = wave + 16;

    const float4* __restrict__ r0 = (const float4*)(x + b0 * RL_N);
    const float4* __restrict__ r1 = (const float4*)(x + b1 * RL_N);

    // Broadcast pivots (same address across the wave -> single transaction).
    const float x0a = x[b0 * RL_N];
    const float x0b = x[b1 * RL_N];

    // Issue ALL loads first: 2048 floats/row = 512 float4; lane l takes
    // float4 index l + 64k, k=0..7 (coalesced, 1 KiB per wave per instr).
    float4 va[8], vb[8];
    #pragma unroll
    for (int k = 0; k < 8; ++k) va[k] = r0[lane + (k << 6)];
    #pragma unroll
    for (int k = 0; k < 8; ++k) vb[k] = r1[lane + (k << 6)];

    float sa = 0.0f, sb = 0.0f;
    #pragma unroll
    for (int k = 0; k < 8; ++k) {
        sa += sig(va[k].x - x0a) + sig(va[k].y - x0a)
            + sig(va[k].z - x0a) + sig(va[k].w - x0a);
        sb += sig(vb[k].x - x0b) + sig(vb[k].y - x0b)
            + sig(vb[k].z - x0b) + sig(vb[k].w - x0b);
    }

    // 64-lane butterfly reductions for both rows.
    #pragma unroll
    for (int off = 32; off > 0; off >>= 1) {
        sa += __shfl_xor(sa, off, 64);
        sb += __shfl_xor(sb, off, 64);
    }

    if (lane == 0) {
        rr_s[b0] = 1.0f / (sa + 0.5f);
        rr_s[b1] = 1.0f / (sb + 0.5f);
    }

    __syncthreads();

    if (tid == 0) {
        float acc = 0.0f;
        #pragma unroll
        for (int b = 0; b < RL_B; ++b) acc += rr_s[b];
        *out = -acc / (float)RL_B;
    }
}

extern "C" void kernel_launch(void* const* d_in, const int* in_sizes, int n_in,
                              void* d_out, int out_size, void* d_ws, size_t ws_size,
                              hipStream_t stream) {
    const float* x = (const float*)d_in[0];
    float* out = (float*)d_out;
    RankLoss_73959336837390_kernel<<<1, 1024, 0, stream>>>(x, out);
}